// Round 1
// baseline (49.446 us; speedup 1.0000x reference)
//
#include <hip/hip_runtime.h>
#include <hip/hip_bf16.h>

// Problem constants (hardcoded in the reference)
#define B_SZ 512
#define D_SZ 1024
#define NK 160
#define NCOL 480          // NK*3
#define OUTW 1184         // D + NK

// ---------------- GEMM: act_t[col][row] = inputs[row][:] . W[:][col] + b[col]
// Tiles: M=32 rows x N=32 cols, K-step 32. Grid (16, 15), 256 threads.
__global__ __launch_bounds__(256) void mbd_gemm_kernel(
    const float* __restrict__ A,      // [512][1024]
    const float* __restrict__ W,      // [1024][480]
    const float* __restrict__ bias,   // [480]
    float* __restrict__ act_t)        // [480][512]
{
    __shared__ float a_s[32][33];     // +1 pad: conflict-free a_s[row][kk] reads
    __shared__ float b_s[32][36];     // +4 pad: keeps float4 reads 16B-aligned

    const int m0 = blockIdx.x * 32;
    const int n0 = blockIdx.y * 32;
    const int tid = threadIdx.x;
    const int row = tid & 31;         // 0..31 (row within tile)
    const int cg  = tid >> 5;         // 0..7  (column group of 4)

    float acc0 = 0.f, acc1 = 0.f, acc2 = 0.f, acc3 = 0.f;

    for (int k0 = 0; k0 < D_SZ; k0 += 32) {
        // stage A tile: 1024 elems, 4 per thread, coalesced
#pragma unroll
        for (int s = 0; s < 4; ++s) {
            int idx = tid + s * 256;
            int r = idx >> 5, kk = idx & 31;
            a_s[r][kk] = A[(m0 + r) * D_SZ + k0 + kk];
        }
        // stage B tile: 1024 elems, 4 per thread, coalesced over columns
#pragma unroll
        for (int s = 0; s < 4; ++s) {
            int idx = tid + s * 256;
            int kk = idx >> 5, c = idx & 31;
            b_s[kk][c] = W[(k0 + kk) * NCOL + n0 + c];
        }
        __syncthreads();
#pragma unroll
        for (int kk = 0; kk < 32; ++kk) {
            const float a = a_s[row][kk];
            const float4 bv = *reinterpret_cast<const float4*>(&b_s[kk][cg * 4]);
            acc0 += a * bv.x;
            acc1 += a * bv.y;
            acc2 += a * bv.z;
            acc3 += a * bv.w;
        }
        __syncthreads();
    }

    // store transposed (+bias): lanes write consecutive rows -> coalesced
    const int col = n0 + cg * 4;
    act_t[(col + 0) * B_SZ + m0 + row] = acc0 + bias[col + 0];
    act_t[(col + 1) * B_SZ + m0 + row] = acc1 + bias[col + 1];
    act_t[(col + 2) * B_SZ + m0 + row] = acc2 + bias[col + 2];
    act_t[(col + 3) * B_SZ + m0 + row] = acc3 + bias[col + 3];
}

// ---------------- Copy inputs -> out[:, 0:1024], float4 coalesced
__global__ __launch_bounds__(256) void mbd_copy_kernel(
    const float* __restrict__ in, float* __restrict__ out)
{
    const int i = blockIdx.x;         // row 0..511
    const int t = threadIdx.x;        // 0..255
    const float4 v = *reinterpret_cast<const float4*>(&in[i * D_SZ + t * 4]);
    *reinterpret_cast<float4*>(&out[i * OUTW + t * 4]) = v;  // OUTW%4==0 -> aligned
}

// ---------------- Pairwise: one block per feature-kernel k.
// feat[i,k] = sum_j exp(-(|d0|+|d1|+|d2|)) over all j (incl. j==i -> +1).
__global__ __launch_bounds__(512) void mbd_pairwise_kernel(
    const float* __restrict__ act_t,  // [480][512]
    float* __restrict__ out)          // [512][1184]
{
    __shared__ float as[B_SZ * 4];    // interleaved x,y,z,pad -> 1 ds_read_b128 per j

    const int k = blockIdx.x;         // 0..159
    const int t = threadIdx.x;        // 0..511 = batch index i

    as[t * 4 + 0] = act_t[(3 * k + 0) * B_SZ + t];
    as[t * 4 + 1] = act_t[(3 * k + 1) * B_SZ + t];
    as[t * 4 + 2] = act_t[(3 * k + 2) * B_SZ + t];
    __syncthreads();

    const float ai0 = as[t * 4 + 0];
    const float ai1 = as[t * 4 + 1];
    const float ai2 = as[t * 4 + 2];

    float acc = 0.f;
#pragma unroll 8
    for (int j = 0; j < B_SZ; ++j) {
        const float4 av = *reinterpret_cast<const float4*>(&as[j * 4]);  // broadcast
        const float d = fabsf(ai0 - av.x) + fabsf(ai1 - av.y) + fabsf(ai2 - av.z);
        acc += __expf(-d);
    }

    out[t * OUTW + D_SZ + k] = acc;
}

extern "C" void kernel_launch(void* const* d_in, const int* in_sizes, int n_in,
                              void* d_out, int out_size, void* d_ws, size_t ws_size,
                              hipStream_t stream)
{
    const float* inputs = (const float*)d_in[0];   // [512,1024]
    const float* W      = (const float*)d_in[1];   // [1024,480]
    const float* bias   = (const float*)d_in[2];   // [480]
    float* out   = (float*)d_out;                  // [512,1184]
    float* act_t = (float*)d_ws;                   // [480,512] = 983 KB scratch

    dim3 ggemm(16, 15);
    mbd_gemm_kernel<<<ggemm, 256, 0, stream>>>(inputs, W, bias, act_t);
    mbd_copy_kernel<<<B_SZ, 256, 0, stream>>>(inputs, out);
    mbd_pairwise_kernel<<<NK, 512, 0, stream>>>(act_t, out);
}